// Round 6
// baseline (116.338 us; speedup 1.0000x reference)
//
#include <hip/hip_runtime.h>

#define INV_T (1.0f / 0.07f)
#define EPSF 1e-8f

typedef __bf16 bf16x8 __attribute__((ext_vector_type(8)));
typedef float f32x4 __attribute__((ext_vector_type(4)));

struct TrueT { static constexpr bool value = true; };
struct FalseT { static constexpr bool value = false; };

__device__ __forceinline__ unsigned short f2b(float x) {
  union { float f; unsigned u; } a; a.f = x;
  return (unsigned short)((a.u + 0x7fffu + ((a.u >> 16) & 1u)) >> 16);
}

__device__ __forceinline__ void gld16(const void* g, void* l) {
  __builtin_amdgcn_global_load_lds(
      (const __attribute__((address_space(1))) unsigned int*)g,
      (__attribute__((address_space(3))) unsigned int*)l, 16, 0, 0);
}

// One wave per row: L2-normalize, cast to bf16. Also zeroes num/den.
__global__ __launch_bounds__(64) void norm_kernel(const float* __restrict__ emb,
                                                  unsigned short* __restrict__ ebf,
                                                  float* __restrict__ num,
                                                  float* __restrict__ den,
                                                  int D) {
  const int row = blockIdx.x;
  const int lane = threadIdx.x;  // 64
  const float4* src = (const float4*)(emb + (size_t)row * D);
  float4 v0 = src[lane];
  float4 v1 = src[lane + 64];
  float ss = v0.x * v0.x + v0.y * v0.y + v0.z * v0.z + v0.w * v0.w +
             v1.x * v1.x + v1.y * v1.y + v1.z * v1.z + v1.w * v1.w;
#pragma unroll
  for (int m = 32; m >= 1; m >>= 1) ss += __shfl_xor(ss, m, 64);
  const float r = 1.0f / sqrtf(ss);
  ushort4 o0, o1;
  o0.x = f2b(v0.x * r); o0.y = f2b(v0.y * r); o0.z = f2b(v0.z * r); o0.w = f2b(v0.w * r);
  o1.x = f2b(v1.x * r); o1.y = f2b(v1.y * r); o1.z = f2b(v1.z * r); o1.w = f2b(v1.w * r);
  ushort4* dst = (ushort4*)(ebf + (size_t)row * D);
  dst[lane] = o0;
  dst[lane + 64] = o1;
  if (lane == 0) { num[row] = 0.f; den[row] = 0.f; }
}

// ---- 8-phase 256x256 GEMM (T3+T4+T5), upper block triangle of e.e^T ----
// BK=64, 8 waves (2Mx4N, wave tile 128x64), 2 LDS buffers (128 KB).
// Per iteration: phases 0-3 read buf0 (tile Te) & stage buf1 (To=Te+1);
//                phases 4-7 read buf1 (To)   & stage buf0 (Te+2).
// Stage units per 4-phase group: {A_q0, B_h0, B_h1, A_q1}; uniform vmcnt(4)
// publishes each unit one phase before its first reader (3-4 phase slack).
// LDS rows are 128 B; swizzle byte ^= ((row&7)<<4) on both stage-source and
// ds_read (G21 both-sides involution) -> 2-way (free) bank access.

// stage one 16 KB unit (2 gld16/thread) of tile `stile` into lds[sbuf].
// unit 0: A rows {0-63,128-191}; 3: A rows {64-127,192-255};
// unit 1: B rows {0-31,64-95,128-159,192-223}; 2: +32.
#define STAGE_UNIT(sbuf, stile, sunit) do {                                    \
  const int kb_ = (stile) * 64;                                                \
  _Pragma("unroll")                                                            \
  for (int sw_ = 0; sw_ < 2; ++sw_) {                                          \
    const int g_ = sw_ * 8 + wave;                                             \
    int r0_;                                                                   \
    if ((sunit) == 0)      r0_ = (g_ >> 3) * 128 + (g_ & 7) * 8;               \
    else if ((sunit) == 3) r0_ = 64 + (g_ >> 3) * 128 + (g_ & 7) * 8;          \
    else if ((sunit) == 1) r0_ = (g_ >> 2) * 64 + (g_ & 3) * 8;                \
    else                   r0_ = 32 + (g_ >> 2) * 64 + (g_ & 3) * 8;           \
    const int mat_ = ((sunit) == 1 || (sunit) == 2) ? 1 : 0;                   \
    const int row_ = r0_ + (lane >> 3);                                        \
    const int colb_ = (lane & 7) * 16;                                         \
    const int scol_ = colb_ ^ ((row_ & 7) << 4);                               \
    const int grow_ = (mat_ ? j0 : i0) + row_;                                 \
    gld16(E + (size_t)grow_ * D + kb_ + (scol_ >> 1),                          \
          &lds[sbuf][mat_][row_ * 64 + (colb_ >> 1)]);                         \
  }                                                                            \
} while (0)

#define PHASE(rbuf, qm, qn, sbuf, stile, sunit, readA, dostage, vmN) do {      \
  const char* Ab_ = (const char*)&lds[rbuf][0][0];                             \
  const char* Bb_ = (const char*)&lds[rbuf][1][0];                             \
  if (readA) {                                                                 \
    _Pragma("unroll")                                                          \
    for (int mm_ = 0; mm_ < 4; ++mm_)                                          \
      _Pragma("unroll")                                                        \
      for (int s_ = 0; s_ < 2; ++s_)                                           \
        aq[mm_][s_] = *(const bf16x8*)(Ab_ + aoff[(qm)*4 + mm_][s_]);          \
  }                                                                            \
  bf16x8 bq_[2][2];                                                            \
  _Pragma("unroll")                                                            \
  for (int nn_ = 0; nn_ < 2; ++nn_)                                            \
    _Pragma("unroll")                                                          \
    for (int s_ = 0; s_ < 2; ++s_)                                             \
      bq_[nn_][s_] = *(const bf16x8*)(Bb_ + boff[(qn)*2 + nn_][s_]);           \
  if (dostage) { STAGE_UNIT(sbuf, stile, sunit); }                             \
  asm volatile("s_waitcnt vmcnt(" #vmN ")" ::: "memory");                      \
  __builtin_amdgcn_s_barrier();                                                \
  asm volatile("s_waitcnt lgkmcnt(0)" ::: "memory");                           \
  __builtin_amdgcn_sched_barrier(0);                                           \
  __builtin_amdgcn_s_setprio(1);                                               \
  _Pragma("unroll")                                                            \
  for (int s_ = 0; s_ < 2; ++s_)                                               \
    _Pragma("unroll")                                                          \
    for (int mm_ = 0; mm_ < 4; ++mm_)                                          \
      _Pragma("unroll")                                                        \
      for (int nn_ = 0; nn_ < 2; ++nn_)                                        \
        acc[(qm)*4 + mm_][(qn)*2 + nn_] =                                      \
            __builtin_amdgcn_mfma_f32_16x16x32_bf16(                           \
                aq[mm_][s_], bq_[nn_][s_],                                     \
                acc[(qm)*4 + mm_][(qn)*2 + nn_], 0, 0, 0);                     \
  __builtin_amdgcn_s_setprio(0);                                               \
  __builtin_amdgcn_s_barrier();                                                \
} while (0)

__global__ __launch_bounds__(512, 2) void sim_kernel(
    const unsigned short* __restrict__ E,   // bf16 normalized, N x D
    const int* __restrict__ labels,         // int32 (harness converts int64)
    float* __restrict__ num, float* __restrict__ den,
    int D, int kTiles) {                    // kTiles = D/64, even
  __shared__ unsigned short lds[2][2][256 * 64];  // [buf][A/B], 32KB each = 128KB

  const int tid = threadIdx.x;
  const int lane = tid & 63;
  const int wave = tid >> 6;               // 0..7
  const int wm = wave >> 2, wn = wave & 3; // 2x4 wave grid: 128x64 per wave
  const int fr = lane & 15;
  const int fk = lane >> 4;

  // XCD-aware swizzle (528 % 8 == 0), then triangular decode
  const int bid = blockIdx.x;
  const int t = (bid & 7) * 66 + (bid >> 3);
  int bb = (int)((sqrtf(8.0f * (float)t + 1.0f) - 1.0f) * 0.5f);
  while ((bb + 1) * (bb + 2) / 2 <= t) ++bb;
  while (bb * (bb + 1) / 2 > t) --bb;
  const int ba = t - bb * (bb + 1) / 2;
  const int i0 = ba * 256;
  const int j0 = bb * 256;
  const bool diag = (i0 == j0);

  f32x4 acc[8][4] = {};
  bf16x8 aq[4][2];

  // ds_read byte offsets: row*128 + ((s*64 + fk*16) ^ ((row&7)<<4))
  int aoff[8][2], boff[4][2];
#pragma unroll
  for (int m = 0; m < 8; ++m) {
    const int row = wm * 128 + m * 16 + fr;
#pragma unroll
    for (int s = 0; s < 2; ++s)
      aoff[m][s] = row * 128 + ((s * 64 + fk * 16) ^ ((row & 7) << 4));
  }
#pragma unroll
  for (int n = 0; n < 4; ++n) {
    const int row = wn * 64 + n * 16 + fr;
#pragma unroll
    for (int s = 0; s < 2; ++s)
      boff[n][s] = row * 128 + ((s * 64 + fk * 16) ^ ((row & 7) << 4));
  }

  // prologue: stage tile 0 fully (units in consumption order), publish first 2
  STAGE_UNIT(0, 0, 0);
  STAGE_UNIT(0, 0, 1);
  STAGE_UNIT(0, 0, 2);
  STAGE_UNIT(0, 0, 3);
  asm volatile("s_waitcnt vmcnt(4)" ::: "memory");
  __builtin_amdgcn_s_barrier();

  const int NIT = kTiles / 2;
  for (int it = 0; it < NIT - 1; ++it) {
    const int To = 2 * it + 1, Tn = 2 * it + 2;
    PHASE(0, 0, 0, 1, To, 0, 1, 1, 4);
    PHASE(0, 0, 1, 1, To, 1, 0, 1, 4);
    PHASE(0, 1, 0, 1, To, 2, 1, 1, 4);
    PHASE(0, 1, 1, 1, To, 3, 0, 1, 4);
    PHASE(1, 0, 0, 0, Tn, 0, 1, 1, 4);
    PHASE(1, 0, 1, 0, Tn, 1, 0, 1, 4);
    PHASE(1, 1, 0, 0, Tn, 2, 1, 1, 4);
    PHASE(1, 1, 1, 0, Tn, 3, 0, 1, 4);
  }
  {  // last iteration: stage To only; tail vmcnt 2,0,0,0
    const int To = kTiles - 1;
    PHASE(0, 0, 0, 1, To, 0, 1, 1, 4);
    PHASE(0, 0, 1, 1, To, 1, 0, 1, 4);
    PHASE(0, 1, 0, 1, To, 2, 1, 1, 4);
    PHASE(0, 1, 1, 1, To, 3, 0, 1, 4);
    PHASE(1, 0, 0, 0, 0, 0, 1, 0, 2);
    PHASE(1, 0, 1, 0, 0, 0, 0, 0, 0);
    PHASE(1, 1, 0, 0, 0, 0, 1, 0, 0);
    PHASE(1, 1, 1, 0, 0, 0, 0, 0, 0);
  }

  // ---- epilogue (verified round 3/5) ----
  // acc[m][n][r]: i = i0 + wm*128 + m*16 + fk*4 + r ; j = j0 + wn*64 + n*16 + fr
  int jcol[4], labj[4];
#pragma unroll
  for (int n = 0; n < 4; ++n) {
    jcol[n] = j0 + wn * 64 + n * 16 + fr;
    labj[n] = labels[jcol[n]];
  }
  float cd[4] = {0.f, 0.f, 0.f, 0.f}, cn[4] = {0.f, 0.f, 0.f, 0.f};

  auto epilogue = [&](auto DIAG) {
#pragma unroll
    for (int m = 0; m < 8; ++m) {
      float pdm[4] = {0.f, 0.f, 0.f, 0.f}, pnm[4] = {0.f, 0.f, 0.f, 0.f};
      const int ibase = i0 + wm * 128 + m * 16 + fk * 4;
      int li[4];
#pragma unroll
      for (int r = 0; r < 4; ++r) li[r] = labels[ibase + r];
#pragma unroll
      for (int n = 0; n < 4; ++n) {
#pragma unroll
        for (int r = 0; r < 4; ++r) {
          const float s = acc[m][n][r] * INV_T;
          const float es = __expf(s);
          if (DIAG.value) {
            if (jcol[n] != ibase + r) {
              pdm[r] += es;
              if (li[r] == labj[n] && s > 0.0f) pnm[r] += es;
            }
          } else {
            pdm[r] += es;
            cd[n] += es;
            if (li[r] == labj[n] && s > 0.0f) { pnm[r] += es; cn[n] += es; }
          }
        }
      }
#pragma unroll
      for (int sh = 1; sh < 16; sh <<= 1) {
#pragma unroll
        for (int r = 0; r < 4; ++r) {
          pdm[r] += __shfl_xor(pdm[r], sh, 64);
          pnm[r] += __shfl_xor(pnm[r], sh, 64);
        }
      }
      if (fr == 0) {
#pragma unroll
        for (int r = 0; r < 4; ++r) {
          atomicAdd(&den[ibase + r], pdm[r]);
          atomicAdd(&num[ibase + r], pnm[r]);
        }
      }
    }
  };

  if (diag) epilogue(TrueT{}); else epilogue(FalseT{});

  if (!diag) {
#pragma unroll
    for (int sh = 16; sh < 64; sh <<= 1) {
#pragma unroll
      for (int n = 0; n < 4; ++n) {
        cd[n] += __shfl_xor(cd[n], sh, 64);
        cn[n] += __shfl_xor(cn[n], sh, 64);
      }
    }
    if (fk == 0) {
#pragma unroll
      for (int n = 0; n < 4; ++n) {
        atomicAdd(&den[jcol[n]], cd[n]);
        atomicAdd(&num[jcol[n]], cn[n]);
      }
    }
  }
}

// Final scalar: loss_i = log(den+eps) - log(num) over valid rows; mean; abs.
__global__ __launch_bounds__(256) void loss_kernel(const float* __restrict__ num,
                                                   const float* __restrict__ den,
                                                   float* __restrict__ out, int N) {
  const int tid = threadIdx.x;
  float sum = 0.f, cnt = 0.f;
  for (int i = tid; i < N; i += 256) {
    const float n = num[i], d = den[i];
    if (n > 0.f && d > 0.f) {
      sum += logf(d + EPSF) - logf(n);
      cnt += 1.f;
    }
  }
#pragma unroll
  for (int m = 32; m >= 1; m >>= 1) {
    sum += __shfl_xor(sum, m, 64);
    cnt += __shfl_xor(cnt, m, 64);
  }
  __shared__ float s1[4], s2[4];
  if ((tid & 63) == 0) { s1[tid >> 6] = sum; s2[tid >> 6] = cnt; }
  __syncthreads();
  if (tid == 0) {
    const float S = s1[0] + s1[1] + s1[2] + s1[3];
    const float C = s2[0] + s2[1] + s2[2] + s2[3];
    out[0] = (C > 0.f) ? fabsf(S / C) : 0.f;
  }
}

extern "C" void kernel_launch(void* const* d_in, const int* in_sizes, int n_in,
                              void* d_out, int out_size, void* d_ws, size_t ws_size,
                              hipStream_t stream) {
  const float* emb = (const float*)d_in[0];
  const int* labels = (const int*)d_in[1];
  float* out = (float*)d_out;

  const int N = in_sizes[1];          // 8192
  const int D = in_sizes[0] / N;      // 512

  unsigned short* ebf = (unsigned short*)d_ws;                 // N*D bf16 = 8 MB
  float* num = (float*)((char*)d_ws + (size_t)N * D * 2);      // N f32
  float* den = num + N;                                        // N f32

  norm_kernel<<<N, 64, 0, stream>>>(emb, ebf, num, den, D);
  const int nb = N / 256;                       // 32
  const int tri = nb * (nb + 1) / 2;            // 528
  sim_kernel<<<tri, 512, 0, stream>>>(ebf, labels, num, den, D, D / 64);
  loss_kernel<<<1, 256, 0, stream>>>(num, den, out, N);
}

// Round 7
// 112.471 us; speedup vs baseline: 1.0344x; 1.0344x over previous
//
#include <hip/hip_runtime.h>

#define INV_T (1.0f / 0.07f)
#define EPSF 1e-8f

typedef __bf16 bf16x8 __attribute__((ext_vector_type(8)));
typedef float f32x4 __attribute__((ext_vector_type(4)));

struct TrueT { static constexpr bool value = true; };
struct FalseT { static constexpr bool value = false; };

__device__ __forceinline__ unsigned short f2b(float x) {
  union { float f; unsigned u; } a; a.f = x;
  return (unsigned short)((a.u + 0x7fffu + ((a.u >> 16) & 1u)) >> 16);
}

__device__ __forceinline__ void gld16(const void* g, void* l) {
  __builtin_amdgcn_global_load_lds(
      (const __attribute__((address_space(1))) unsigned int*)g,
      (__attribute__((address_space(3))) unsigned int*)l, 16, 0, 0);
}

// One wave per row: L2-normalize, cast to bf16. Also zeroes num/den.
__global__ __launch_bounds__(64) void norm_kernel(const float* __restrict__ emb,
                                                  unsigned short* __restrict__ ebf,
                                                  float* __restrict__ num,
                                                  float* __restrict__ den,
                                                  int D) {
  const int row = blockIdx.x;
  const int lane = threadIdx.x;  // 64
  const float4* src = (const float4*)(emb + (size_t)row * D);
  float4 v0 = src[lane];
  float4 v1 = src[lane + 64];
  float ss = v0.x * v0.x + v0.y * v0.y + v0.z * v0.z + v0.w * v0.w +
             v1.x * v1.x + v1.y * v1.y + v1.z * v1.z + v1.w * v1.w;
#pragma unroll
  for (int m = 32; m >= 1; m >>= 1) ss += __shfl_xor(ss, m, 64);
  const float r = 1.0f / sqrtf(ss);
  ushort4 o0, o1;
  o0.x = f2b(v0.x * r); o0.y = f2b(v0.y * r); o0.z = f2b(v0.z * r); o0.w = f2b(v0.w * r);
  o1.x = f2b(v1.x * r); o1.y = f2b(v1.y * r); o1.z = f2b(v1.z * r); o1.w = f2b(v1.w * r);
  ushort4* dst = (ushort4*)(ebf + (size_t)row * D);
  dst[lane] = o0;
  dst[lane + 64] = o1;
  if (lane == 0) { num[row] = 0.f; den[row] = 0.f; }
}

// Upper-block-triangle of sim = e.e^T. 256x256 tile, BK=32, 8 waves (2Mx4N).
// 2-phase double-buffer, 64KB LDS -> 2 blocks/CU: cross-block wave overlap
// hides the per-tile vmcnt drain (m114). Off-diagonal blocks scatter each exp
// term to BOTH row i and col j. LDS swizzle: byte ^= (((row>>1)&3)<<4), G21
// both-sides (inverse-swizzled global source, swizzled ds_read), 2-way free.
__global__ __launch_bounds__(512, 2) void sim_kernel(
    const unsigned short* __restrict__ E,   // bf16 normalized, N x D
    const int* __restrict__ labels,         // int32 (harness converts int64)
    float* __restrict__ num, float* __restrict__ den,
    int D, int kTiles) {
  __shared__ unsigned short lds[2][2][256 * 32];  // [buf][A/B], 16KB each, 64KB

  const int tid = threadIdx.x;
  const int lane = tid & 63;
  const int wave = tid >> 6;               // 0..7
  const int wm = wave >> 2, wn = wave & 3; // 2x4 wave grid: 128x64 per wave
  const int fr = lane & 15;                // fragment row/col index
  const int fk = lane >> 4;                // k-group

  // XCD-aware swizzle (528 % 8 == 0 -> simple bijective form), then
  // triangular decode: t = bb*(bb+1)/2 + ba, ba <= bb
  const int bid = blockIdx.x;
  const int t = (bid & 7) * 66 + (bid >> 3);
  int bb = (int)((sqrtf(8.0f * (float)t + 1.0f) - 1.0f) * 0.5f);
  while ((bb + 1) * (bb + 2) / 2 <= t) ++bb;
  while (bb * (bb + 1) / 2 > t) --bb;
  const int ba = t - bb * (bb + 1) / 2;
  const int i0 = ba * 256;
  const int j0 = bb * 256;
  const bool diag = (i0 == j0);

  f32x4 acc[8][4] = {};

  // per-thread constant LDS fragment byte offsets (swizzle XOR is fr-only)
  const int swz = ((fr >> 1) & 3) << 4;
  const int cbk = (fk * 16) ^ swz;
  int aoff[8], boff[4];
#pragma unroll
  for (int m = 0; m < 8; ++m) aoff[m] = (wm * 128 + m * 16 + fr) * 64 + cbk;
#pragma unroll
  for (int n = 0; n < 4; ++n) boff[n] = (wn * 64 + n * 16 + fr) * 64 + cbk;

  // stage one K-tile (256 rows x 32 cols per matrix, 16KB each) into buf.
  // LDS dest linear (wave-uniform base + lane*16); source col inverse-swizzled.
  auto stage = [&](int buf, int kt) {
    const int kbase = kt * 32;
#pragma unroll
    for (int c = 0; c < 2; ++c) {
      const int lo = c * 8192 + tid * 16;            // byte offset in 16KB tile
      const int row = lo >> 6;                       // 64B per row
      const int scb = (lo & 63) ^ (((row >> 1) & 3) << 4);
      const unsigned short* gA = E + (size_t)(i0 + row) * D + kbase + (scb >> 1);
      const unsigned short* gB = E + (size_t)(j0 + row) * D + kbase + (scb >> 1);
      gld16(gA, &lds[buf][0][lo >> 1]);
      gld16(gB, &lds[buf][1][lo >> 1]);
    }
  };

  auto compute = [&](int cb) {
    const char* Ab = (const char*)&lds[cb][0][0];
    const char* Bb = (const char*)&lds[cb][1][0];
    bf16x8 a[8], b[4];
#pragma unroll
    for (int m = 0; m < 8; ++m) a[m] = *(const bf16x8*)(Ab + aoff[m]);
#pragma unroll
    for (int n = 0; n < 4; ++n) b[n] = *(const bf16x8*)(Bb + boff[n]);
    __builtin_amdgcn_s_setprio(1);
#pragma unroll
    for (int m = 0; m < 8; ++m)
#pragma unroll
      for (int n = 0; n < 4; ++n)
        acc[m][n] = __builtin_amdgcn_mfma_f32_16x16x32_bf16(a[m], b[n], acc[m][n], 0, 0, 0);
    __builtin_amdgcn_s_setprio(0);
  };

  // prologue: stage tile 0, drain, barrier
  stage(0, 0);
  asm volatile("s_waitcnt vmcnt(0)" ::: "memory");
  __builtin_amdgcn_s_barrier();

  // T3-minimum 2-phase: stage(next) -> compute(cur) -> drain -> barrier.
  // One vmcnt(0)+barrier per K-tile; the stall overlaps the co-resident
  // block's compute/epilogue (2 blocks/CU).
  int cur = 0;
  for (int kt = 0; kt < kTiles; ++kt) {
    if (kt + 1 < kTiles) stage(cur ^ 1, kt + 1);
    compute(cur);
    asm volatile("s_waitcnt vmcnt(0) lgkmcnt(0)" ::: "memory");
    __builtin_amdgcn_s_barrier();
    cur ^= 1;
  }

  // ---- epilogue (verified rounds 3/5/6) ----
  // acc[m][n][r]: i = i0 + wm*128 + m*16 + fk*4 + r ; j = j0 + wn*64 + n*16 + fr
  int jcol[4], labj[4];
#pragma unroll
  for (int n = 0; n < 4; ++n) {
    jcol[n] = j0 + wn * 64 + n * 16 + fr;
    labj[n] = labels[jcol[n]];
  }
  float cd[4] = {0.f, 0.f, 0.f, 0.f}, cn[4] = {0.f, 0.f, 0.f, 0.f};

  auto epilogue = [&](auto DIAG) {
#pragma unroll
    for (int m = 0; m < 8; ++m) {
      float pdm[4] = {0.f, 0.f, 0.f, 0.f}, pnm[4] = {0.f, 0.f, 0.f, 0.f};
      const int ibase = i0 + wm * 128 + m * 16 + fk * 4;
      int li[4];
#pragma unroll
      for (int r = 0; r < 4; ++r) li[r] = labels[ibase + r];
#pragma unroll
      for (int n = 0; n < 4; ++n) {
#pragma unroll
        for (int r = 0; r < 4; ++r) {
          const float s = acc[m][n][r] * INV_T;
          const float es = __expf(s);
          if (DIAG.value) {
            if (jcol[n] != ibase + r) {
              pdm[r] += es;
              if (li[r] == labj[n] && s > 0.0f) pnm[r] += es;
            }
          } else {
            pdm[r] += es;
            cd[n] += es;
            if (li[r] == labj[n] && s > 0.0f) { pnm[r] += es; cn[n] += es; }
          }
        }
      }
#pragma unroll
      for (int sh = 1; sh < 16; sh <<= 1) {
#pragma unroll
        for (int r = 0; r < 4; ++r) {
          pdm[r] += __shfl_xor(pdm[r], sh, 64);
          pnm[r] += __shfl_xor(pnm[r], sh, 64);
        }
      }
      if (fr == 0) {
#pragma unroll
        for (int r = 0; r < 4; ++r) {
          atomicAdd(&den[ibase + r], pdm[r]);
          atomicAdd(&num[ibase + r], pnm[r]);
        }
      }
    }
  };

  if (diag) epilogue(TrueT{}); else epilogue(FalseT{});

  if (!diag) {
#pragma unroll
    for (int sh = 16; sh < 64; sh <<= 1) {
#pragma unroll
      for (int n = 0; n < 4; ++n) {
        cd[n] += __shfl_xor(cd[n], sh, 64);
        cn[n] += __shfl_xor(cn[n], sh, 64);
      }
    }
    if (fk == 0) {
#pragma unroll
      for (int n = 0; n < 4; ++n) {
        atomicAdd(&den[jcol[n]], cd[n]);
        atomicAdd(&num[jcol[n]], cn[n]);
      }
    }
  }
}

// Final scalar: loss_i = log(den+eps) - log(num) over valid rows; mean; abs.
__global__ __launch_bounds__(256) void loss_kernel(const float* __restrict__ num,
                                                   const float* __restrict__ den,
                                                   float* __restrict__ out, int N) {
  const int tid = threadIdx.x;
  float sum = 0.f, cnt = 0.f;
  for (int i = tid; i < N; i += 256) {
    const float n = num[i], d = den[i];
    if (n > 0.f && d > 0.f) {
      sum += logf(d + EPSF) - logf(n);
      cnt += 1.f;
    }
  }
#pragma unroll
  for (int m = 32; m >= 1; m >>= 1) {
    sum += __shfl_xor(sum, m, 64);
    cnt += __shfl_xor(cnt, m, 64);
  }
  __shared__ float s1[4], s2[4];
  if ((tid & 63) == 0) { s1[tid >> 6] = sum; s2[tid >> 6] = cnt; }
  __syncthreads();
  if (tid == 0) {
    const float S = s1[0] + s1[1] + s1[2] + s1[3];
    const float C = s2[0] + s2[1] + s2[2] + s2[3];
    out[0] = (C > 0.f) ? fabsf(S / C) : 0.f;
  }
}

extern "C" void kernel_launch(void* const* d_in, const int* in_sizes, int n_in,
                              void* d_out, int out_size, void* d_ws, size_t ws_size,
                              hipStream_t stream) {
  const float* emb = (const float*)d_in[0];
  const int* labels = (const int*)d_in[1];
  float* out = (float*)d_out;

  const int N = in_sizes[1];          // 8192
  const int D = in_sizes[0] / N;      // 512

  unsigned short* ebf = (unsigned short*)d_ws;                 // N*D bf16 = 8 MB
  float* num = (float*)((char*)d_ws + (size_t)N * D * 2);      // N f32
  float* den = num + N;                                        // N f32

  norm_kernel<<<N, 64, 0, stream>>>(emb, ebf, num, den, D);
  const int nb = N / 256;                       // 32
  const int tri = nb * (nb + 1) / 2;            // 528
  sim_kernel<<<tri, 512, 0, stream>>>(ebf, labels, num, den, D, D / 32);
  loss_kernel<<<1, 256, 0, stream>>>(num, den, out, N);
}